// Round 1
// baseline (396.637 us; speedup 1.0000x reference)
//
#include <hip/hip_runtime.h>

// ArcFace loss, MI355X. B=512, D=512, C=64000, s=64, m=0.5.
// R8 = persistent-block pipeline. Timed region = 2x ~78us harness poison
// fills (fixed) + our ~65us. gemm was ~55-60us vs a ~20-25us floor because
// phase-0 (W stream) and the K-loop (MFMA) ran lockstep across the two
// co-resident blocks. New structure: grid=250 persistent blocks, 4 tiles
// of 64 classes each, sW double-buffered (128 KB LDS, 1 block/CU).
// Next tile's W rows are nt-loaded into registers INSIDE the K-loop
// (issue k=1,3,5,7; normalize+LDS-write k=9,11,13,15 after that step's
// MFMAs) -> HBM stream continuous, MFMA hidden under it, 1 barrier/tile.
// esum accumulated in registers across tiles -> 1 atomic per row/block.

#define B_N 512
#define D_N 512
#define C_N 64000
#define S_SCALE 64.0f
#define MARGIN 0.5f
#define EPS_C 1e-7f
#define NREP 16
#define TPB 4          // 64-class tiles per block
#define GRID_GEMM 250  // 250 * 4 * 64 = 64000 classes

typedef unsigned short ushort_t;
typedef __attribute__((ext_vector_type(8))) short short8;   // 8 bf16 (4 VGPRs)
typedef __attribute__((ext_vector_type(4))) float floatx4;  // MFMA acc
typedef __attribute__((ext_vector_type(4))) float fvec4;    // nt loads

__device__ __forceinline__ ushort_t f2bf(float f) {
    unsigned int u = __float_as_uint(f);
    u += 0x7fffu + ((u >> 16) & 1u);  // round-to-nearest-even
    return (ushort_t)(u >> 16);
}

// Normalize x rows -> bf16 in fragment-linear layout:
//   xnT element addr = (kc*512 + row)*8 + j,  kc = k/8 in [0,64), j = k%8.
// Blocks 0..127: 4 rows each. Block 128: zero rowsum replicas.
__global__ void xprep_kernel(const float* __restrict__ x,
                             ushort_t* __restrict__ xnT,
                             float* __restrict__ rowsumR) {
    int b = blockIdx.x;
    int t = threadIdx.x;
    if (b == 128) {
#pragma unroll
        for (int i = 0; i < NREP * B_N / 256; ++i)
            rowsumR[i * 256 + t] = 0.0f;
        return;
    }
    int row  = b * 4 + (t >> 6);
    int lane = t & 63;
    const float4* p = (const float4*)(x + (size_t)row * D_N);
    float4 v0 = p[lane * 2];        // elems [lane*8 .. lane*8+3]
    float4 v1 = p[lane * 2 + 1];    // elems [lane*8+4 .. lane*8+7]
    float ss = v0.x*v0.x + v0.y*v0.y + v0.z*v0.z + v0.w*v0.w
             + v1.x*v1.x + v1.y*v1.y + v1.z*v1.z + v1.w*v1.w;
#pragma unroll
    for (int off = 32; off > 0; off >>= 1) ss += __shfl_xor(ss, off);
    float sc = 1.0f / fmaxf(sqrtf(ss), 1e-12f);
    uint4 o;
    o.x = (unsigned)f2bf(v0.x*sc) | ((unsigned)f2bf(v0.y*sc) << 16);
    o.y = (unsigned)f2bf(v0.z*sc) | ((unsigned)f2bf(v0.w*sc) << 16);
    o.z = (unsigned)f2bf(v1.x*sc) | ((unsigned)f2bf(v1.y*sc) << 16);
    o.w = (unsigned)f2bf(v1.z*sc) | ((unsigned)f2bf(v1.w*sc) << 16);
    *((uint4*)(xnT + ((size_t)(lane << 9) + row) * 8)) = o;
}

// Persistent block: 4 tiles x (64 classes x 512 rows). 8 waves; wave w owns
// rows [w*64, w*64+64) x tile cols [0,64) as 4x4 mfma_f32_16x16x32_bf16.
// sW (XOR swizzle): addr = kc*512 + (row^(kc&7))*8 + k&7, 0 conflicts.
__global__ __launch_bounds__(512, 2)
void gemm_fused_kernel(const float* __restrict__ W,
                       const ushort_t* __restrict__ xnT,
                       const int* __restrict__ y,
                       float* __restrict__ rowsumR,
                       float* __restrict__ tgt) {
    __shared__ ushort_t sW[2][64 * 512];  // 128 KB double-buffered B operand

    int t     = threadIdx.x;
    int lane  = t & 63;
    int w     = t >> 6;     // wave 0..7
    int lq    = lane >> 4;  // quad
    int lc    = lane & 15;
    int cbase = blockIdx.x * (TPB * 64);

    // A-frag pointers into fragment-linear xnT (same for every tile).
    const ushort_t* apT[4];
#pragma unroll
    for (int tm = 0; tm < 4; tm++)
        apT[tm] = xnT + ((size_t)lq * 512 + w * 64 + tm * 16 + lc) * 8;

    float esum[4][4];
#pragma unroll
    for (int tm = 0; tm < 4; tm++)
#pragma unroll
        for (int r = 0; r < 4; r++) esum[tm][r] = 0.0f;

    // ---- prologue: stage + normalize tile 0 into sW[0] ----
#pragma unroll
    for (int rr = 0; rr < 8; ++rr) {
        int row = w * 8 + rr;
        const fvec4* p = (const fvec4*)(W + (size_t)(cbase + row) * D_N);
        fvec4 a = __builtin_nontemporal_load(p + lane * 2);
        fvec4 b = __builtin_nontemporal_load(p + lane * 2 + 1);
        float ss = a.x*a.x + a.y*a.y + a.z*a.z + a.w*a.w
                 + b.x*b.x + b.y*b.y + b.z*b.z + b.w*b.w;
#pragma unroll
        for (int off = 32; off > 0; off >>= 1) ss += __shfl_xor(ss, off);
        float sc = 1.0f / fmaxf(sqrtf(ss), 1e-12f);
        uint4 o;
        o.x = (unsigned)f2bf(a.x*sc) | ((unsigned)f2bf(a.y*sc) << 16);
        o.y = (unsigned)f2bf(a.z*sc) | ((unsigned)f2bf(a.w*sc) << 16);
        o.z = (unsigned)f2bf(b.x*sc) | ((unsigned)f2bf(b.y*sc) << 16);
        o.w = (unsigned)f2bf(b.z*sc) | ((unsigned)f2bf(b.w*sc) << 16);
        int kc = lane;
        int rs = row ^ (kc & 7);
        *((uint4*)(&sW[0][kc * 512 + rs * 8])) = o;
    }
    __syncthreads();

    int cur = 0;
    for (int tt = 0; tt < TPB; ++tt) {
        const int  cn0     = cbase + tt * 64;
        const bool notlast = (tt < TPB - 1);
        const ushort_t* sWc = sW[cur];
        ushort_t*       sWn = sW[cur ^ 1];
        const int  nb      = cn0 + 64;  // next tile's class base

        floatx4 acc[4][4];
#pragma unroll
        for (int i = 0; i < 4; i++)
#pragma unroll
            for (int j = 0; j < 4; j++) acc[i][j] = (floatx4){0.f, 0.f, 0.f, 0.f};

        short8 af[4];
#pragma unroll
        for (int tm = 0; tm < 4; tm++) af[tm] = *(const short8*)(apT[tm]);

        fvec4 wA[8], wB[8];  // next-tile W rows staged in registers

#pragma unroll
        for (int k = 0; k < 16; ++k) {
            // A-frag prefetch for k+1 (from L2-resident xnT)
            short8 afn[4];
            if (k < 15) {
#pragma unroll
                for (int tm = 0; tm < 4; tm++)
                    afn[tm] = *(const short8*)(apT[tm] + (k + 1) * 16384);
            }
            // W stage ISSUE: 2 rows per batch at k = 1,3,5,7 (nt; keeps
            // xnT L2-resident). Issued before MFMA so HBM latency hides
            // under ~8 k-steps of compute before the consume.
            if (notlast && (k == 1 || k == 3 || k == 5 || k == 7)) {
                const int bi = (k - 1) >> 1;
#pragma unroll
                for (int rx = 0; rx < 2; ++rx) {
                    int row = w * 8 + bi * 2 + rx;
                    const fvec4* p = (const fvec4*)(W + (size_t)(nb + row) * D_N);
                    wA[bi * 2 + rx] = __builtin_nontemporal_load(p + lane * 2);
                    wB[bi * 2 + rx] = __builtin_nontemporal_load(p + lane * 2 + 1);
                }
            }
            // B frags (swizzled LDS) + 16 MFMA
            const int kc = k * 4 + lq;
            short8 bfr[4];
#pragma unroll
            for (int tn = 0; tn < 4; tn++) {
                int rs = (tn * 16 + lc) ^ (kc & 7);
                bfr[tn] = *(const short8*)(&sWc[kc * 512 + rs * 8]);
            }
#pragma unroll
            for (int tm = 0; tm < 4; tm++)
#pragma unroll
                for (int tn = 0; tn < 4; tn++)
                    acc[tm][tn] = __builtin_amdgcn_mfma_f32_16x16x32_bf16(
                        af[tm], bfr[tn], acc[tm][tn], 0, 0, 0);
            // W stage CONSUME: normalize + write to sW[nxt] at k=9,11,13,15
            // (after this step's MFMAs; sW[nxt] has no readers this tile).
            if (notlast && (k == 9 || k == 11 || k == 13 || k == 15)) {
                const int bi = (k - 9) >> 1;
#pragma unroll
                for (int rx = 0; rx < 2; ++rx) {
                    int row = w * 8 + bi * 2 + rx;
                    fvec4 a = wA[bi * 2 + rx];
                    fvec4 b = wB[bi * 2 + rx];
                    float ss = a.x*a.x + a.y*a.y + a.z*a.z + a.w*a.w
                             + b.x*b.x + b.y*b.y + b.z*b.z + b.w*b.w;
#pragma unroll
                    for (int off = 32; off > 0; off >>= 1) ss += __shfl_xor(ss, off);
                    float sc = 1.0f / fmaxf(sqrtf(ss), 1e-12f);
                    uint4 o;
                    o.x = (unsigned)f2bf(a.x*sc) | ((unsigned)f2bf(a.y*sc) << 16);
                    o.y = (unsigned)f2bf(a.z*sc) | ((unsigned)f2bf(a.w*sc) << 16);
                    o.z = (unsigned)f2bf(b.x*sc) | ((unsigned)f2bf(b.y*sc) << 16);
                    o.w = (unsigned)f2bf(b.z*sc) | ((unsigned)f2bf(b.w*sc) << 16);
                    int kcs = lane;
                    int rs  = row ^ (kcs & 7);
                    *((uint4*)(&sWn[kcs * 512 + rs * 8])) = o;
                }
            }
            if (k < 15) {
#pragma unroll
                for (int tm = 0; tm < 4; tm++) af[tm] = afn[tm];
            }
        }

        // ---- per-tile epilogue: C/D layout col=lane&15, row=lq*4+reg ----
#pragma unroll
        for (int tm = 0; tm < 4; tm++) {
#pragma unroll
            for (int r = 0; r < 4; r++) {
                int grow = w * 64 + tm * 16 + lq * 4 + r;  // batch row
                int yv   = y[grow];
                float es = 0.0f;
#pragma unroll
                for (int tn = 0; tn < 4; tn++) {
                    int gcol = cn0 + tn * 16 + lc;
                    float theta = acc[tm][tn][r];
                    if (gcol == yv) {
                        tgt[grow] = theta;  // exactly one writer device-wide
                    } else {
                        es += __expf(S_SCALE * theta);
                    }
                }
                esum[tm][r] += es;
            }
        }
        __syncthreads();  // sWn complete + all waves done reading sWc
        cur ^= 1;
    }

    // ---- final: reduce esum across 16 lc lanes, 1 atomic per row ----
#pragma unroll
    for (int tm = 0; tm < 4; tm++) {
#pragma unroll
        for (int r = 0; r < 4; r++) {
            float e = esum[tm][r];
#pragma unroll
            for (int off = 1; off < 16; off <<= 1) e += __shfl_xor(e, off);
            if (lc == 0) {
                int grow = w * 64 + tm * 16 + lq * 4 + r;
                atomicAdd(&rowsumR[(blockIdx.x & (NREP - 1)) * B_N + grow], e);
            }
        }
    }
}

__global__ void finalize_kernel(const float* __restrict__ rowsumR,
                                const float* __restrict__ tgt,
                                float* __restrict__ out) {
    __shared__ float red[256];
    int t = threadIdx.x;
    float s = 0.0f;
    for (int r = t; r < B_N; r += 256) {
        float rs = 0.0f;
#pragma unroll
        for (int i = 0; i < NREP; ++i) rs += rowsumR[i * B_N + r];
        float tv = tgt[r];
        tv = fminf(fmaxf(tv, -1.0f + EPS_C), 1.0f - EPS_C);
        float num = S_SCALE * cosf(acosf(tv) + MARGIN);
        float den = expf(num) + rs;
        s += num - logf(den);
    }
    red[t] = s;
    __syncthreads();
    for (int o = 128; o > 0; o >>= 1) {
        if (t < o) red[t] += red[t + o];
        __syncthreads();
    }
    if (t == 0) out[0] = -red[0] / (float)B_N;
}

extern "C" void kernel_launch(void* const* d_in, const int* in_sizes, int n_in,
                              void* d_out, int out_size, void* d_ws, size_t ws_size,
                              hipStream_t stream) {
    const float* x = (const float*)d_in[0];
    const int*   y = (const int*)d_in[1];
    const float* W = (const float*)d_in[2];
    float* out = (float*)d_out;

    char* ws = (char*)d_ws;
    ushort_t* xnT   = (ushort_t*)ws;                    // 512 KB (frag-linear)
    float* rowsumR  = (float*)(ws + 524288);            // 32 KB (16 replicas)
    float* tgt      = rowsumR + NREP * B_N;             // 2 KB

    xprep_kernel<<<129, 256, 0, stream>>>(x, xnT, rowsumR);
    gemm_fused_kernel<<<GRID_GEMM, 512, 0, stream>>>(W, xnT, y, rowsumR, tgt);
    finalize_kernel<<<1, 256, 0, stream>>>(rowsumR, tgt, out);
}